// Round 4
// baseline (127.616 us; speedup 1.0000x reference)
//
#include <hip/hip_runtime.h>

#define SB 8
#define SS 2048
#define SD 1024
#define SH 64

typedef float f32x4 __attribute__((ext_vector_type(4)));
typedef __bf16 bf16x8 __attribute__((ext_vector_type(8)));

__device__ __forceinline__ unsigned short f2bf(float f) {
  union { float f; unsigned int u; } v; v.f = f;
  unsigned int u = v.u;
  unsigned int r = u + 0x7FFFu + ((u >> 16) & 1u);
  return (unsigned short)(r >> 16);
}

// Wt[hc][d] = W_{hc/64}[d][hc&63] as bf16, hc in [0,192), d in [0,1024)
__global__ void prep_wt(const float* __restrict__ Wq, const float* __restrict__ Wk,
                        const float* __restrict__ Wv, unsigned short* __restrict__ Wt) {
  int idx = blockIdx.x * 256 + threadIdx.x;
  int hc = idx >> 10, d = idx & 1023;
  const float* W = (hc < 64) ? Wq : (hc < 128) ? Wk : Wv;
  int h = hc & 63;
  Wt[idx] = f2bf(W[d * SH + h]);
}

// QKV projection: M=16384, N=192, K=1024. 512 blocks x 512 thr (2 blocks/CU).
// Block = 32 rows x 192 cols; wave = 16 rows x 48 cols (acc[3]).
// x tile (32x64) staged f32->bf16 into XOR-swizzled LDS; A-prefetch in regs;
// B-frags (L2-resident Wt) double-buffered in regs, prefetched one K-step ahead.
__global__ void __launch_bounds__(512, 4) proj(
    const float* __restrict__ x, const unsigned short* __restrict__ Wt,
    unsigned short* __restrict__ Q, unsigned short* __restrict__ K,
    unsigned short* __restrict__ Vt) {
  __shared__ unsigned short xs[32 * 64];  // 4 KB, 16B-granule XOR swizzle

  int tid = threadIdx.x;
  int w = tid >> 6, lane = tid & 63;
  int l15 = lane & 15, kg = lane >> 4;
  int wr = w >> 2, wc = w & 3;
  int m0 = blockIdx.x * 32;

  // staging: 16 thr/row, 4 f32 each -> one b64 LDS write after cvt
  int srow = tid >> 4, sseg = tid & 15;
  const float* xp = x + (size_t)(m0 + srow) * SD + sseg * 4;
  unsigned short* swp = xs + srow * 64 + (((sseg >> 1) ^ (srow & 7)) << 3) + ((sseg & 1) << 2);

  const unsigned short* wb0 = Wt + (size_t)(wc * 48 + l15) * SD + kg * 8;

  f32x4 acc[3];
#pragma unroll
  for (int nt = 0; nt < 3; ++nt) acc[nt] = f32x4{0.f, 0.f, 0.f, 0.f};

  bf16x8 bu[6], bp[6];
#define LOADB(dst, tt)                                                          \
  {                                                                             \
    _Pragma("unroll") for (int ks = 0; ks < 2; ++ks)                            \
      _Pragma("unroll") for (int nt = 0; nt < 3; ++nt)                          \
        (dst)[ks * 3 + nt] =                                                    \
            *(const bf16x8*)(wb0 + (size_t)nt * 16 * SD + (tt) * 64 + ks * 32); \
  }

#define STEP(tt, BU, BP, DOPRE)                                                 \
  {                                                                             \
    ushort4 cv;                                                                 \
    cv.x = f2bf(ra.x); cv.y = f2bf(ra.y);                                       \
    cv.z = f2bf(ra.z); cv.w = f2bf(ra.w);                                       \
    *(ushort4*)swp = cv;                                                        \
    __syncthreads();                                                            \
    if (DOPRE) {                                                                \
      ra = *(const float4*)(xp + ((tt) + 1) * 64);                              \
      LOADB(BP, (tt) + 1);                                                      \
    }                                                                           \
    _Pragma("unroll") for (int ks = 0; ks < 2; ++ks) {                          \
      int row = wr * 16 + l15;                                                  \
      bf16x8 af = *(const bf16x8*)(xs + row * 64 +                              \
                                   (((ks * 4 + kg) ^ (row & 7)) << 3));         \
      _Pragma("unroll") for (int nt = 0; nt < 3; ++nt)                          \
        acc[nt] = __builtin_amdgcn_mfma_f32_16x16x32_bf16(af, (BU)[ks * 3 + nt],\
                                                          acc[nt], 0, 0, 0);    \
    }                                                                           \
    __syncthreads();                                                            \
  }

  float4 ra = *(const float4*)xp;
  LOADB(bu, 0);
  for (int t = 0; t < 16; t += 2) {
    STEP(t, bu, bp, 1);
    STEP(t + 1, bp, bu, (t < 14));
  }

#pragma unroll
  for (int nt = 0; nt < 3; ++nt) {
    int c = wc * 48 + nt * 16 + l15;
    int mat = c >> 6, h = c & 63;
#pragma unroll
    for (int r = 0; r < 4; ++r) {
      int row = m0 + wr * 16 + kg * 4 + r;
      unsigned short bv = f2bf(acc[nt][r]);
      if (mat == 0) {
        Q[(size_t)row * SH + h] = bv;
      } else if (mat == 1) {
        K[(size_t)row * SH + h] = bv;
      } else {
        int bb = row >> 11, key = row & 2047;
        Vt[((size_t)bb * SH + h) * SS + key] = bv;
      }
    }
  }
}

// Attention, single pass, KV-split x8. 1024 blocks x 512 thr.
// Block = (batch b = bid&7 for XCD locality, rowgroup rg = bid>>3).
// Wave: 16 q-rows x 256 keys; raw scores in regs; weights stored direct from
// regs; P staged as bf16 in LDS (psh) so PV A-frags are 2x ds_read_b128.
__global__ void __launch_bounds__(512, 4) attn(
    const unsigned short* __restrict__ Q, const unsigned short* __restrict__ Kb,
    const unsigned short* __restrict__ Vt, float* __restrict__ out,
    float* __restrict__ wts) {
  __shared__ unsigned short psh[8][16][72];  // per-wave bf16 P tile
  __shared__ float cf[8][16][68];            // PV partial combine
  __shared__ float mS[8][16], sgS[8][16];

  int b = blockIdx.x & 7, rg = blockIdx.x >> 3;
  int w = threadIdx.x >> 6, lane = threadIdx.x & 63;
  int l15 = lane & 15, kg = lane >> 4;
  int q0 = rg * 16;
  int kv0 = w * 256;

  const unsigned short* Qb  = Q  + (size_t)b * SS * SH;
  const unsigned short* Kbb = Kb + (size_t)b * SS * SH;
  const unsigned short* Vtb = Vt + (size_t)b * SH * SS;

  bf16x8 qf[2];
#pragma unroll
  for (int ks = 0; ks < 2; ++ks)
    qf[ks] = *(const bf16x8*)(Qb + (size_t)(q0 + l15) * SH + ks * 32 + kg * 8);

  // ---- QK^T over this wave's 256-key slice; raw scores stay in registers
  f32x4 s[4][4];
#pragma unroll
  for (int kt = 0; kt < 4; ++kt)
#pragma unroll
    for (int n = 0; n < 4; ++n) s[kt][n] = f32x4{0.f, 0.f, 0.f, 0.f};

  for (int kt = 0; kt < 4; ++kt) {
#pragma unroll
    for (int ks = 0; ks < 2; ++ks)
#pragma unroll
      for (int n = 0; n < 4; ++n) {
        bf16x8 kf = *(const bf16x8*)(Kbb + (size_t)(kv0 + kt * 64 + n * 16 + l15) * SH + ks * 32 + kg * 8);
        s[kt][n] = __builtin_amdgcn_mfma_f32_16x16x32_bf16(qf[ks], kf, s[kt][n], 0, 0, 0);
      }
  }

  // ---- local softmax stats; convert s -> e = exp(s*scale - m_loc) in-place
  float m[4], sg[4];
#pragma unroll
  for (int r = 0; r < 4; ++r) {
    float mloc = -1e30f;
#pragma unroll
    for (int kt = 0; kt < 4; ++kt)
#pragma unroll
      for (int n = 0; n < 4; ++n) mloc = fmaxf(mloc, s[kt][n][r]);
    mloc *= 0.125f;
#pragma unroll
    for (int off = 1; off < 16; off <<= 1) mloc = fmaxf(mloc, __shfl_xor(mloc, off));
    float ssum = 0.f;
#pragma unroll
    for (int kt = 0; kt < 4; ++kt)
#pragma unroll
      for (int n = 0; n < 4; ++n) {
        float e = __expf(s[kt][n][r] * 0.125f - mloc);
        s[kt][n][r] = e;
        ssum += e;
      }
#pragma unroll
    for (int off = 1; off < 16; off <<= 1) ssum += __shfl_xor(ssum, off);
    m[r] = mloc; sg[r] = ssum;
  }

  if (l15 == 0) {
#pragma unroll
    for (int r = 0; r < 4; ++r) {
      mS[w][kg * 4 + r] = m[r];
      sgS[w][kg * 4 + r] = sg[r];
    }
  }
  __syncthreads();

  // ---- global stats -> per-row scale for this wave's slice
  float scal[4];
#pragma unroll
  for (int r = 0; r < 4; ++r) {
    int row = kg * 4 + r;
    float M = -1e30f;
#pragma unroll
    for (int ww = 0; ww < 8; ++ww) M = fmaxf(M, mS[ww][row]);
    float Sg = 0.f;
#pragma unroll
    for (int ww = 0; ww < 8; ++ww) Sg += sgS[ww][row] * __expf(mS[ww][row] - M);
    scal[r] = __expf(m[r] - M) / Sg;
  }

  float* wtp = wts + (size_t)b * SS * SS + (size_t)q0 * SS + kv0;
  f32x4 oacc[4];
#pragma unroll
  for (int nh = 0; nh < 4; ++nh) oacc[nh] = f32x4{0.f, 0.f, 0.f, 0.f};

  // ---- per 64-key tile: normalize in regs -> {direct global stores, bf16 LDS, PV}
  for (int kt = 0; kt < 4; ++kt) {
#pragma unroll
    for (int n = 0; n < 4; ++n)
#pragma unroll
      for (int r = 0; r < 4; ++r) {
        float p = s[kt][n][r] * scal[r];
        wtp[(size_t)(kg * 4 + r) * SS + kt * 64 + n * 16 + l15] = p;
        psh[w][kg * 4 + r][n * 16 + l15] = f2bf(p);
      }

#pragma unroll
    for (int ks = 0; ks < 2; ++ks) {
      bf16x8 pu = *(const bf16x8*)&psh[w][l15][ks * 32 + kg * 8];
#pragma unroll
      for (int nh = 0; nh < 4; ++nh) {
        bf16x8 vf = *(const bf16x8*)(Vtb + (size_t)(nh * 16 + l15) * SS + kv0 + kt * 64 + ks * 32 + kg * 8);
        oacc[nh] = __builtin_amdgcn_mfma_f32_16x16x32_bf16(pu, vf, oacc[nh], 0, 0, 0);
      }
    }
  }

  // ---- combine partial PV across the 8 waves via LDS
#pragma unroll
  for (int nh = 0; nh < 4; ++nh)
#pragma unroll
    for (int r = 0; r < 4; ++r)
      cf[w][kg * 4 + r][nh * 16 + l15] = oacc[nh][r];
  __syncthreads();

  int tid = threadIdx.x;
#pragma unroll
  for (int half = 0; half < 2; ++half) {
    int e = tid + half * 512;
    int row = e >> 6, col = e & 63;
    float ssum = 0.f;
#pragma unroll
    for (int ww = 0; ww < 8; ++ww) ssum += cf[ww][row][col];
    out[((size_t)b * SS + q0 + row) * SH + col] = ssum;
  }
}

extern "C" void kernel_launch(void* const* d_in, const int* in_sizes, int n_in,
                              void* d_out, int out_size, void* d_ws, size_t ws_size,
                              hipStream_t stream) {
  const float* x  = (const float*)d_in[0];
  const float* Wq = (const float*)d_in[1];
  const float* Wk = (const float*)d_in[2];
  const float* Wv = (const float*)d_in[3];

  unsigned short* Wt = (unsigned short*)d_ws;                 // 192*1024
  unsigned short* Q  = Wt + 192 * 1024;                       // 16384*64
  unsigned short* K  = Q + 16384 * 64;                        // 16384*64
  unsigned short* Vt = K + 16384 * 64;                        // 8*64*2048

  float* out = (float*)d_out;
  float* wts = out + (size_t)SB * SS * SH;

  prep_wt<<<768, 256, 0, stream>>>(Wq, Wk, Wv, Wt);
  proj<<<512, 512, 0, stream>>>(x, Wt, Q, K, Vt);
  attn<<<1024, 512, 0, stream>>>(Q, K, Vt, out, wts);
}

// Round 5
// 127.523 us; speedup vs baseline: 1.0007x; 1.0007x over previous
//
#include <hip/hip_runtime.h>

#define SB 8
#define SS 2048
#define SD 1024
#define SH 64

typedef float f32x4 __attribute__((ext_vector_type(4)));
typedef __bf16 bf16x8 __attribute__((ext_vector_type(8)));

__device__ __forceinline__ unsigned short f2bf(float f) {
  union { float f; unsigned int u; } v; v.f = f;
  unsigned int u = v.u;
  unsigned int r = u + 0x7FFFu + ((u >> 16) & 1u);
  return (unsigned short)(r >> 16);
}

// Wt[hc][d] = W_{hc/64}[d][hc&63] as bf16, hc in [0,192), d in [0,1024)
__global__ void prep_wt(const float* __restrict__ Wq, const float* __restrict__ Wk,
                        const float* __restrict__ Wv, unsigned short* __restrict__ Wt) {
  int idx = blockIdx.x * 256 + threadIdx.x;
  int hc = idx >> 10, d = idx & 1023;
  const float* W = (hc < 64) ? Wq : (hc < 128) ? Wk : Wv;
  int h = hc & 63;
  Wt[idx] = f2bf(W[d * SH + h]);
}

// QKV projection: M=16384, N=192, K=1024. 512 blocks x 512 thr (2 blocks/CU).
// Block = 32 rows x 192 cols; wave = 16 rows x 48 cols (acc[3]).
// Double-buffered LDS x-tile (1 barrier/step), reg-double-buffered B-frags,
// x prefetched 2 steps ahead.
__global__ void __launch_bounds__(512, 4) proj(
    const float* __restrict__ x, const unsigned short* __restrict__ Wt,
    unsigned short* __restrict__ Q, unsigned short* __restrict__ K,
    unsigned short* __restrict__ Vt) {
  __shared__ unsigned short xs[2][32 * 64];  // 2 x 4 KB, 16B-granule XOR swizzle

  int tid = threadIdx.x;
  int w = tid >> 6, lane = tid & 63;
  int l15 = lane & 15, kg = lane >> 4;
  int wr = w >> 2, wc = w & 3;
  int m0 = blockIdx.x * 32;

  // staging: 16 thr/row, 4 f32 each -> one b64 LDS write after cvt
  int srow = tid >> 4, sseg = tid & 15;
  const float* xp = x + (size_t)(m0 + srow) * SD + sseg * 4;
  int swoff = srow * 64 + (((sseg >> 1) ^ (srow & 7)) << 3) + ((sseg & 1) << 2);

  const unsigned short* wb0 = Wt + (size_t)(wc * 48 + l15) * SD + kg * 8;

  f32x4 acc[3];
#pragma unroll
  for (int nt = 0; nt < 3; ++nt) acc[nt] = f32x4{0.f, 0.f, 0.f, 0.f};

  bf16x8 bu[6], bp[6];

#define LOADB(dst, tt)                                                          \
  {                                                                             \
    _Pragma("unroll") for (int ks = 0; ks < 2; ++ks)                            \
      _Pragma("unroll") for (int nt = 0; nt < 3; ++nt)                          \
        (dst)[ks * 3 + nt] =                                                    \
            *(const bf16x8*)(wb0 + (size_t)nt * 16 * SD + (tt) * 64 + ks * 32); \
  }

#define CVTW(RA, buf)                                                           \
  {                                                                             \
    ushort4 cv;                                                                 \
    cv.x = f2bf((RA).x); cv.y = f2bf((RA).y);                                   \
    cv.z = f2bf((RA).z); cv.w = f2bf((RA).w);                                   \
    *(ushort4*)(&xs[(buf)][0] + swoff) = cv;                                    \
  }

#define MFMAS(BU, buf)                                                          \
  {                                                                             \
    _Pragma("unroll") for (int ks = 0; ks < 2; ++ks) {                          \
      int row = wr * 16 + l15;                                                  \
      bf16x8 af = *(const bf16x8*)(&xs[(buf)][0] + row * 64 +                   \
                                   (((ks * 4 + kg) ^ (row & 7)) << 3));         \
      _Pragma("unroll") for (int nt = 0; nt < 3; ++nt)                          \
        acc[nt] = __builtin_amdgcn_mfma_f32_16x16x32_bf16(af, (BU)[ks * 3 + nt],\
                                                          acc[nt], 0, 0, 0);    \
    }                                                                           \
  }

#define STEP(tt, BU, BP)                                                        \
  {                                                                             \
    if ((tt) < 15) CVTW(ra, ((tt) + 1) & 1);                                    \
    if ((tt) < 14) ra = *(const float4*)(xp + ((tt) + 2) * 64);                 \
    if ((tt) < 15) LOADB(BP, (tt) + 1);                                         \
    MFMAS(BU, (tt) & 1);                                                        \
    __syncthreads();                                                            \
  }

  float4 r0 = *(const float4*)xp;        // x(0)
  LOADB(bu, 0);
  CVTW(r0, 0);
  float4 ra = *(const float4*)(xp + 64); // x(1)
  __syncthreads();

  for (int t = 0; t < 16; t += 2) {
    STEP(t, bu, bp);
    STEP(t + 1, bp, bu);
  }

#pragma unroll
  for (int nt = 0; nt < 3; ++nt) {
    int c = wc * 48 + nt * 16 + l15;
    int mat = c >> 6, h = c & 63;
#pragma unroll
    for (int r = 0; r < 4; ++r) {
      int row = m0 + wr * 16 + kg * 4 + r;
      unsigned short bv = f2bf(acc[nt][r]);
      if (mat == 0) {
        Q[(size_t)row * SH + h] = bv;
      } else if (mat == 1) {
        K[(size_t)row * SH + h] = bv;
      } else {
        int bb = row >> 11, key = row & 2047;
        Vt[((size_t)bb * SH + h) * SS + key] = bv;
      }
    }
  }
}

// Attention, single pass, KV-split x8. 1024 blocks x 512 thr, 4 blocks/CU.
// psh (bf16 P, PV phase) and cf (f32 combine, epilogue) alias one LDS buffer:
// disjoint lifetimes separated by a barrier -> 36 KB total, 32 waves/CU.
__global__ void __launch_bounds__(512, 4) attn(
    const unsigned short* __restrict__ Q, const unsigned short* __restrict__ Kb,
    const unsigned short* __restrict__ Vt, float* __restrict__ out,
    float* __restrict__ wts) {
  __shared__ __align__(16) float shbuf[8 * 16 * 68];  // 34.8 KB shared arena
  __shared__ float mS[8][16], sgS[8][16];
  unsigned short (*psh)[16][72] = (unsigned short (*)[16][72])shbuf;
  float (*cf)[16][68] = (float (*)[16][68])shbuf;

  int b = blockIdx.x & 7, rg = blockIdx.x >> 3;
  int w = threadIdx.x >> 6, lane = threadIdx.x & 63;
  int l15 = lane & 15, kg = lane >> 4;
  int q0 = rg * 16;
  int kv0 = w * 256;

  const unsigned short* Qb  = Q  + (size_t)b * SS * SH;
  const unsigned short* Kbb = Kb + (size_t)b * SS * SH;
  const unsigned short* Vtb = Vt + (size_t)b * SH * SS;

  bf16x8 qf[2];
#pragma unroll
  for (int ks = 0; ks < 2; ++ks)
    qf[ks] = *(const bf16x8*)(Qb + (size_t)(q0 + l15) * SH + ks * 32 + kg * 8);

  // ---- QK^T over this wave's 256-key slice; raw scores stay in registers
  f32x4 s[4][4];
#pragma unroll
  for (int kt = 0; kt < 4; ++kt)
#pragma unroll
    for (int n = 0; n < 4; ++n) s[kt][n] = f32x4{0.f, 0.f, 0.f, 0.f};

  for (int kt = 0; kt < 4; ++kt) {
#pragma unroll
    for (int ks = 0; ks < 2; ++ks)
#pragma unroll
      for (int n = 0; n < 4; ++n) {
        bf16x8 kf = *(const bf16x8*)(Kbb + (size_t)(kv0 + kt * 64 + n * 16 + l15) * SH + ks * 32 + kg * 8);
        s[kt][n] = __builtin_amdgcn_mfma_f32_16x16x32_bf16(qf[ks], kf, s[kt][n], 0, 0, 0);
      }
  }

  // ---- local softmax stats; convert s -> e = exp(s*scale - m_loc) in-place
  float m[4], sg[4];
#pragma unroll
  for (int r = 0; r < 4; ++r) {
    float mloc = -1e30f;
#pragma unroll
    for (int kt = 0; kt < 4; ++kt)
#pragma unroll
      for (int n = 0; n < 4; ++n) mloc = fmaxf(mloc, s[kt][n][r]);
    mloc *= 0.125f;
#pragma unroll
    for (int off = 1; off < 16; off <<= 1) mloc = fmaxf(mloc, __shfl_xor(mloc, off));
    float ssum = 0.f;
#pragma unroll
    for (int kt = 0; kt < 4; ++kt)
#pragma unroll
      for (int n = 0; n < 4; ++n) {
        float e = __expf(s[kt][n][r] * 0.125f - mloc);
        s[kt][n][r] = e;
        ssum += e;
      }
#pragma unroll
    for (int off = 1; off < 16; off <<= 1) ssum += __shfl_xor(ssum, off);
    m[r] = mloc; sg[r] = ssum;
  }

  if (l15 == 0) {
#pragma unroll
    for (int r = 0; r < 4; ++r) {
      mS[w][kg * 4 + r] = m[r];
      sgS[w][kg * 4 + r] = sg[r];
    }
  }
  __syncthreads();

  // ---- global stats -> per-row scale for this wave's slice
  float scal[4];
#pragma unroll
  for (int r = 0; r < 4; ++r) {
    int row = kg * 4 + r;
    float M = -1e30f;
#pragma unroll
    for (int ww = 0; ww < 8; ++ww) M = fmaxf(M, mS[ww][row]);
    float Sg = 0.f;
#pragma unroll
    for (int ww = 0; ww < 8; ++ww) Sg += sgS[ww][row] * __expf(mS[ww][row] - M);
    scal[r] = __expf(m[r] - M) / Sg;
  }

  float* wtp = wts + (size_t)b * SS * SS + (size_t)q0 * SS + kv0;
  f32x4 oacc[4];
#pragma unroll
  for (int nh = 0; nh < 4; ++nh) oacc[nh] = f32x4{0.f, 0.f, 0.f, 0.f};

  // ---- per 64-key tile: normalize in regs -> {direct global stores, bf16 LDS, PV}
  for (int kt = 0; kt < 4; ++kt) {
#pragma unroll
    for (int n = 0; n < 4; ++n)
#pragma unroll
      for (int r = 0; r < 4; ++r) {
        float p = s[kt][n][r] * scal[r];
        wtp[(size_t)(kg * 4 + r) * SS + kt * 64 + n * 16 + l15] = p;
        psh[w][kg * 4 + r][n * 16 + l15] = f2bf(p);
      }

#pragma unroll
    for (int ks = 0; ks < 2; ++ks) {
      bf16x8 pu = *(const bf16x8*)&psh[w][l15][ks * 32 + kg * 8];
#pragma unroll
      for (int nh = 0; nh < 4; ++nh) {
        bf16x8 vf = *(const bf16x8*)(Vtb + (size_t)(nh * 16 + l15) * SS + kv0 + kt * 64 + ks * 32 + kg * 8);
        oacc[nh] = __builtin_amdgcn_mfma_f32_16x16x32_bf16(pu, vf, oacc[nh], 0, 0, 0);
      }
    }
  }

  // ---- psh lifetime ends; alias the arena as cf for the partial-PV combine
  __syncthreads();
#pragma unroll
  for (int nh = 0; nh < 4; ++nh)
#pragma unroll
    for (int r = 0; r < 4; ++r)
      cf[w][kg * 4 + r][nh * 16 + l15] = oacc[nh][r];
  __syncthreads();

  int tid = threadIdx.x;
#pragma unroll
  for (int half = 0; half < 2; ++half) {
    int e = tid + half * 512;
    int row = e >> 6, col = e & 63;
    float ssum = 0.f;
#pragma unroll
    for (int ww = 0; ww < 8; ++ww) ssum += cf[ww][row][col];
    out[((size_t)b * SS + q0 + row) * SH + col] = ssum;
  }
}

extern "C" void kernel_launch(void* const* d_in, const int* in_sizes, int n_in,
                              void* d_out, int out_size, void* d_ws, size_t ws_size,
                              hipStream_t stream) {
  const float* x  = (const float*)d_in[0];
  const float* Wq = (const float*)d_in[1];
  const float* Wk = (const float*)d_in[2];
  const float* Wv = (const float*)d_in[3];

  unsigned short* Wt = (unsigned short*)d_ws;                 // 192*1024
  unsigned short* Q  = Wt + 192 * 1024;                       // 16384*64
  unsigned short* K  = Q + 16384 * 64;                        // 16384*64
  unsigned short* Vt = K + 16384 * 64;                        // 8*64*2048

  float* out = (float*)d_out;
  float* wts = out + (size_t)SB * SS * SH;

  prep_wt<<<768, 256, 0, stream>>>(Wq, Wk, Wv, Wt);
  proj<<<512, 512, 0, stream>>>(x, Wt, Q, K, Vt);
  attn<<<1024, 512, 0, stream>>>(Q, K, Vt, out, wts);
}

// Round 6
// 119.873 us; speedup vs baseline: 1.0646x; 1.0638x over previous
//
#include <hip/hip_runtime.h>

#define SB 8
#define SS 2048
#define SD 1024
#define SH 64

typedef float f32x4 __attribute__((ext_vector_type(4)));
typedef __bf16 bf16x8 __attribute__((ext_vector_type(8)));

__device__ __forceinline__ unsigned short f2bf(float f) {
  union { float f; unsigned int u; } v; v.f = f;
  unsigned int u = v.u;
  unsigned int r = u + 0x7FFFu + ((u >> 16) & 1u);
  return (unsigned short)(r >> 16);
}

// Wt[hc][d] = W_{hc/64}[d][hc&63] as bf16, hc in [0,192), d in [0,1024)
__global__ void prep_wt(const float* __restrict__ Wq, const float* __restrict__ Wk,
                        const float* __restrict__ Wv, unsigned short* __restrict__ Wt) {
  int idx = blockIdx.x * 256 + threadIdx.x;
  int hc = idx >> 10, d = idx & 1023;
  const float* W = (hc < 64) ? Wq : (hc < 128) ? Wk : Wv;
  int h = hc & 63;
  Wt[idx] = f2bf(W[d * SH + h]);
}

// QKV projection (round-3 proven structure, 46.8us): M=16384, N=192, K=1024.
// 256 blocks x 512 thr. Block = 64 rows x 192 cols; wave = 32 rows x 48 cols.
// x tile staged f32->bf16 into XOR-swizzled LDS; next tile prefetched into regs
// during the MFMA phase. Wt B-frags direct from global (L2-resident, 384 KB).
__global__ void __launch_bounds__(512, 2) proj(
    const float* __restrict__ x, const unsigned short* __restrict__ Wt,
    unsigned short* __restrict__ Q, unsigned short* __restrict__ K,
    unsigned short* __restrict__ Vt) {
  __shared__ unsigned short xs[64 * 64];  // 8 KB, cg ^= (row&7) swizzle

  int tid = threadIdx.x;
  int w = tid >> 6, lane = tid & 63;
  int l15 = lane & 15, kg = lane >> 4;
  int wr = w >> 2, wc = w & 3;
  int m0 = blockIdx.x * 64;

  // staging map: 8 threads/row, 8 f32 each (one b128 LDS write after cvt)
  int srow = tid >> 3, sseg = tid & 7;
  const float* xp = x + (size_t)(m0 + srow) * SD + sseg * 8;
  unsigned short* swp = xs + srow * 64 + ((sseg ^ (srow & 7)) * 8);

  float4 ra = *(const float4*)xp;
  float4 rb = *(const float4*)(xp + 4);

  f32x4 acc[2][3];
#pragma unroll
  for (int mt = 0; mt < 2; ++mt)
#pragma unroll
    for (int nt = 0; nt < 3; ++nt) acc[mt][nt] = f32x4{0.f, 0.f, 0.f, 0.f};

  for (int t = 0; t < 16; ++t) {
    union { unsigned short us[8]; bf16x8 v; } cv;
    cv.us[0] = f2bf(ra.x); cv.us[1] = f2bf(ra.y);
    cv.us[2] = f2bf(ra.z); cv.us[3] = f2bf(ra.w);
    cv.us[4] = f2bf(rb.x); cv.us[5] = f2bf(rb.y);
    cv.us[6] = f2bf(rb.z); cv.us[7] = f2bf(rb.w);
    *(bf16x8*)swp = cv.v;
    __syncthreads();

    if (t < 15) {
      ra = *(const float4*)(xp + (t + 1) * 64);
      rb = *(const float4*)(xp + (t + 1) * 64 + 4);
    }

    int k0 = t * 64;
#pragma unroll
    for (int ks = 0; ks < 2; ++ks) {
      bf16x8 af[2];
#pragma unroll
      for (int mt = 0; mt < 2; ++mt) {
        int row = wr * 32 + mt * 16 + l15;
        int cg = ks * 4 + kg;
        af[mt] = *(const bf16x8*)(xs + row * 64 + ((cg ^ (row & 7)) * 8));
      }
#pragma unroll
      for (int nt = 0; nt < 3; ++nt) {
        int c = wc * 48 + nt * 16 + l15;
        bf16x8 bfr = *(const bf16x8*)(Wt + (size_t)c * SD + k0 + ks * 32 + kg * 8);
#pragma unroll
        for (int mt = 0; mt < 2; ++mt)
          acc[mt][nt] = __builtin_amdgcn_mfma_f32_16x16x32_bf16(af[mt], bfr, acc[mt][nt], 0, 0, 0);
      }
    }
    __syncthreads();
  }

#pragma unroll
  for (int nt = 0; nt < 3; ++nt) {
    int c = wc * 48 + nt * 16 + l15;
    int mat = c >> 6, h = c & 63;
#pragma unroll
    for (int mt = 0; mt < 2; ++mt)
#pragma unroll
      for (int r = 0; r < 4; ++r) {
        int row = m0 + wr * 32 + mt * 16 + kg * 4 + r;
        unsigned short bv = f2bf(acc[mt][nt][r]);
        if (mat == 0) {
          Q[(size_t)row * SH + h] = bv;
        } else if (mat == 1) {
          K[(size_t)row * SH + h] = bv;
        } else {
          int bb = row >> 11, key = row & 2047;
          Vt[((size_t)bb * SH + h) * SS + key] = bv;
        }
      }
  }
}

// Attention, single pass, KV-split x8, SWAPPED QK^T: s = mfma(K, Q) so
// D cols = q-rows (l15), D rows = k (kg*4+r): each lane owns ONE q-row with
// 4-consecutive-k groups -> f32x4 weight stores direct from accumulators,
// b64 psh writes, 2-shuffle softmax reduce.
// 1024 blocks x 512 thr, 4 blocks/CU (psh/cf alias one 34.8 KB arena).
__global__ void __launch_bounds__(512, 4) attn(
    const unsigned short* __restrict__ Q, const unsigned short* __restrict__ Kb,
    const unsigned short* __restrict__ Vt, float* __restrict__ out,
    float* __restrict__ wts) {
  __shared__ __align__(16) float shbuf[8 * 16 * 68];  // 34.8 KB shared arena
  __shared__ float mS[8][16], sgS[8][16];
  unsigned short (*psh)[16][72] = (unsigned short (*)[16][72])shbuf;
  float (*cf)[16][68] = (float (*)[16][68])shbuf;

  int b = blockIdx.x & 7, rg = blockIdx.x >> 3;
  int w = threadIdx.x >> 6, lane = threadIdx.x & 63;
  int l15 = lane & 15, kg = lane >> 4;
  int q0 = rg * 16;
  int kv0 = w * 256;

  const unsigned short* Qb  = Q  + (size_t)b * SS * SH;
  const unsigned short* Kbb = Kb + (size_t)b * SS * SH;
  const unsigned short* Vtb = Vt + (size_t)b * SH * SS;

  bf16x8 qf[2];
#pragma unroll
  for (int ks = 0; ks < 2; ++ks)
    qf[ks] = *(const bf16x8*)(Qb + (size_t)(q0 + l15) * SH + ks * 32 + kg * 8);

  // ---- QK^T (swapped): s[kt][n][r] = S[k = kv0+kt*64+n*16+kg*4+r][q = q0+l15]
  f32x4 s[4][4];
#pragma unroll
  for (int kt = 0; kt < 4; ++kt)
#pragma unroll
    for (int n = 0; n < 4; ++n) s[kt][n] = f32x4{0.f, 0.f, 0.f, 0.f};

  for (int kt = 0; kt < 4; ++kt) {
#pragma unroll
    for (int ks = 0; ks < 2; ++ks)
#pragma unroll
      for (int n = 0; n < 4; ++n) {
        bf16x8 kf = *(const bf16x8*)(Kbb + (size_t)(kv0 + kt * 64 + n * 16 + l15) * SH + ks * 32 + kg * 8);
        s[kt][n] = __builtin_amdgcn_mfma_f32_16x16x32_bf16(kf, qf[ks], s[kt][n], 0, 0, 0);
      }
  }

  // ---- local softmax stats; lane owns one q-row, 64 k-values
  float mloc = -1e30f;
#pragma unroll
  for (int kt = 0; kt < 4; ++kt)
#pragma unroll
    for (int n = 0; n < 4; ++n)
#pragma unroll
      for (int r = 0; r < 4; ++r) mloc = fmaxf(mloc, s[kt][n][r]);
  mloc *= 0.125f;
  mloc = fmaxf(mloc, __shfl_xor(mloc, 16));
  mloc = fmaxf(mloc, __shfl_xor(mloc, 32));

  float ssum = 0.f;
#pragma unroll
  for (int kt = 0; kt < 4; ++kt)
#pragma unroll
    for (int n = 0; n < 4; ++n)
#pragma unroll
      for (int r = 0; r < 4; ++r) {
        float e = __expf(s[kt][n][r] * 0.125f - mloc);
        s[kt][n][r] = e;
        ssum += e;
      }
  ssum += __shfl_xor(ssum, 16);
  ssum += __shfl_xor(ssum, 32);

  if (lane < 16) {
    mS[w][l15] = mloc;
    sgS[w][l15] = ssum;
  }
  __syncthreads();

  // ---- global stats -> per-lane scale for its q-row
  float M = -1e30f;
#pragma unroll
  for (int ww = 0; ww < 8; ++ww) M = fmaxf(M, mS[ww][l15]);
  float Sg = 0.f;
#pragma unroll
  for (int ww = 0; ww < 8; ++ww) Sg += sgS[ww][l15] * __expf(mS[ww][l15] - M);
  float scal = __expf(mloc - M) / Sg;

  float* wtp = wts + (size_t)b * SS * SS + (size_t)(q0 + l15) * SS + kv0;
  f32x4 oacc[4];
#pragma unroll
  for (int nh = 0; nh < 4; ++nh) oacc[nh] = f32x4{0.f, 0.f, 0.f, 0.f};

  // ---- per 64-key tile: normalize -> {f32x4 weight store, b64 psh write, PV}
  for (int kt = 0; kt < 4; ++kt) {
#pragma unroll
    for (int n = 0; n < 4; ++n) {
      f32x4 pv;
#pragma unroll
      for (int r = 0; r < 4; ++r) pv[r] = s[kt][n][r] * scal;
      *(f32x4*)(wtp + kt * 64 + n * 16 + kg * 4) = pv;
      ushort4 pb;
      pb.x = f2bf(pv[0]); pb.y = f2bf(pv[1]);
      pb.z = f2bf(pv[2]); pb.w = f2bf(pv[3]);
      *(ushort4*)&psh[w][l15][n * 16 + kg * 4] = pb;
    }

#pragma unroll
    for (int ks = 0; ks < 2; ++ks) {
      bf16x8 pu = *(const bf16x8*)&psh[w][l15][ks * 32 + kg * 8];
#pragma unroll
      for (int nh = 0; nh < 4; ++nh) {
        bf16x8 vf = *(const bf16x8*)(Vtb + (size_t)(nh * 16 + l15) * SS + kv0 + kt * 64 + ks * 32 + kg * 8);
        oacc[nh] = __builtin_amdgcn_mfma_f32_16x16x32_bf16(pu, vf, oacc[nh], 0, 0, 0);
      }
    }
  }

  // ---- psh lifetime ends; alias the arena as cf for the partial-PV combine
  __syncthreads();
#pragma unroll
  for (int nh = 0; nh < 4; ++nh)
#pragma unroll
    for (int r = 0; r < 4; ++r)
      cf[w][kg * 4 + r][nh * 16 + l15] = oacc[nh][r];
  __syncthreads();

  int tid = threadIdx.x;
#pragma unroll
  for (int half = 0; half < 2; ++half) {
    int e = tid + half * 512;
    int row = e >> 6, col = e & 63;
    float ssum2 = 0.f;
#pragma unroll
    for (int ww = 0; ww < 8; ++ww) ssum2 += cf[ww][row][col];
    out[((size_t)b * SS + q0 + row) * SH + col] = ssum2;
  }
}

extern "C" void kernel_launch(void* const* d_in, const int* in_sizes, int n_in,
                              void* d_out, int out_size, void* d_ws, size_t ws_size,
                              hipStream_t stream) {
  const float* x  = (const float*)d_in[0];
  const float* Wq = (const float*)d_in[1];
  const float* Wk = (const float*)d_in[2];
  const float* Wv = (const float*)d_in[3];

  unsigned short* Wt = (unsigned short*)d_ws;                 // 192*1024
  unsigned short* Q  = Wt + 192 * 1024;                       // 16384*64
  unsigned short* K  = Q + 16384 * 64;                        // 16384*64
  unsigned short* Vt = K + 16384 * 64;                        // 8*64*2048

  float* out = (float*)d_out;
  float* wts = out + (size_t)SB * SS * SH;

  prep_wt<<<768, 256, 0, stream>>>(Wq, Wk, Wv, Wt);
  proj<<<256, 512, 0, stream>>>(x, Wt, Q, K, Vt);
  attn<<<1024, 512, 0, stream>>>(Q, K, Vt, out, wts);
}

// Round 7
// 115.662 us; speedup vs baseline: 1.1034x; 1.0364x over previous
//
#include <hip/hip_runtime.h>

#define SB 8
#define SS 2048
#define SD 1024
#define SH 64

typedef float f32x4 __attribute__((ext_vector_type(4)));
typedef __bf16 bf16x8 __attribute__((ext_vector_type(8)));

__device__ __forceinline__ unsigned short f2bf(float f) {
  union { float f; unsigned int u; } v; v.f = f;
  unsigned int u = v.u;
  unsigned int r = u + 0x7FFFu + ((u >> 16) & 1u);
  return (unsigned short)(r >> 16);
}

// Wt[hc][d] = W_{hc/64}[d][hc&63] as bf16, hc in [0,192), d in [0,1024)
__global__ void prep_wt(const float* __restrict__ Wq, const float* __restrict__ Wk,
                        const float* __restrict__ Wv, unsigned short* __restrict__ Wt) {
  int idx = blockIdx.x * 256 + threadIdx.x;
  int hc = idx >> 10, d = idx & 1023;
  const float* W = (hc < 64) ? Wq : (hc < 128) ? Wk : Wv;
  int h = hc & 63;
  Wt[idx] = f2bf(W[d * SH + h]);
}

// QKV projection (round-3 proven structure, ~37us): M=16384, N=192, K=1024.
// 256 blocks x 512 thr. Block = 64 rows x 192 cols; wave = 32 rows x 48 cols.
__global__ void __launch_bounds__(512, 2) proj(
    const float* __restrict__ x, const unsigned short* __restrict__ Wt,
    unsigned short* __restrict__ Q, unsigned short* __restrict__ K,
    unsigned short* __restrict__ Vt) {
  __shared__ unsigned short xs[64 * 64];  // 8 KB, cg ^= (row&7) swizzle

  int tid = threadIdx.x;
  int w = tid >> 6, lane = tid & 63;
  int l15 = lane & 15, kg = lane >> 4;
  int wr = w >> 2, wc = w & 3;
  int m0 = blockIdx.x * 64;

  int srow = tid >> 3, sseg = tid & 7;
  const float* xp = x + (size_t)(m0 + srow) * SD + sseg * 8;
  unsigned short* swp = xs + srow * 64 + ((sseg ^ (srow & 7)) * 8);

  float4 ra = *(const float4*)xp;
  float4 rb = *(const float4*)(xp + 4);

  f32x4 acc[2][3];
#pragma unroll
  for (int mt = 0; mt < 2; ++mt)
#pragma unroll
    for (int nt = 0; nt < 3; ++nt) acc[mt][nt] = f32x4{0.f, 0.f, 0.f, 0.f};

  for (int t = 0; t < 16; ++t) {
    union { unsigned short us[8]; bf16x8 v; } cv;
    cv.us[0] = f2bf(ra.x); cv.us[1] = f2bf(ra.y);
    cv.us[2] = f2bf(ra.z); cv.us[3] = f2bf(ra.w);
    cv.us[4] = f2bf(rb.x); cv.us[5] = f2bf(rb.y);
    cv.us[6] = f2bf(rb.z); cv.us[7] = f2bf(rb.w);
    *(bf16x8*)swp = cv.v;
    __syncthreads();

    if (t < 15) {
      ra = *(const float4*)(xp + (t + 1) * 64);
      rb = *(const float4*)(xp + (t + 1) * 64 + 4);
    }

    int k0 = t * 64;
#pragma unroll
    for (int ks = 0; ks < 2; ++ks) {
      bf16x8 af[2];
#pragma unroll
      for (int mt = 0; mt < 2; ++mt) {
        int row = wr * 32 + mt * 16 + l15;
        int cg = ks * 4 + kg;
        af[mt] = *(const bf16x8*)(xs + row * 64 + ((cg ^ (row & 7)) * 8));
      }
#pragma unroll
      for (int nt = 0; nt < 3; ++nt) {
        int c = wc * 48 + nt * 16 + l15;
        bf16x8 bfr = *(const bf16x8*)(Wt + (size_t)c * SD + k0 + ks * 32 + kg * 8);
#pragma unroll
        for (int mt = 0; mt < 2; ++mt)
          acc[mt][nt] = __builtin_amdgcn_mfma_f32_16x16x32_bf16(af[mt], bfr, acc[mt][nt], 0, 0, 0);
      }
    }
    __syncthreads();
  }

#pragma unroll
  for (int nt = 0; nt < 3; ++nt) {
    int c = wc * 48 + nt * 16 + l15;
    int mat = c >> 6, h = c & 63;
#pragma unroll
    for (int mt = 0; mt < 2; ++mt)
#pragma unroll
      for (int r = 0; r < 4; ++r) {
        int row = m0 + wr * 32 + mt * 16 + kg * 4 + r;
        unsigned short bv = f2bf(acc[mt][nt][r]);
        if (mat == 0) {
          Q[(size_t)row * SH + h] = bv;
        } else if (mat == 1) {
          K[(size_t)row * SH + h] = bv;
        } else {
          int bb = row >> 11, key = row & 2047;
          Vt[((size_t)bb * SH + h) * SS + key] = bv;
        }
      }
  }
}

// Attention, single pass, KV-split x8, swapped QK^T (cheap per-lane softmax),
// P routed through per-wave f32 LDS slice -> fully coalesced f32x4 weight
// stores (16 full 64B lines per instruction) + PV A-frags from 2x b128 reads.
// 1024 blocks x 512 thr, 35.8 KB LDS -> 4 blocks/CU. pf reused for combine.
__global__ void __launch_bounds__(512, 4) attn(
    const unsigned short* __restrict__ Q, const unsigned short* __restrict__ Kb,
    const unsigned short* __restrict__ Vt, float* __restrict__ out,
    float* __restrict__ wts) {
  __shared__ __align__(16) float pf[8][16][68];  // 34.8 KB, per-wave slices
  __shared__ float mS[8][16], sgS[8][16];

  int b = blockIdx.x & 7, rg = blockIdx.x >> 3;
  int w = threadIdx.x >> 6, lane = threadIdx.x & 63;
  int l15 = lane & 15, kg = lane >> 4;
  int q0 = rg * 16;
  int kv0 = w * 256;

  const unsigned short* Qb  = Q  + (size_t)b * SS * SH;
  const unsigned short* Kbb = Kb + (size_t)b * SS * SH;
  const unsigned short* Vtb = Vt + (size_t)b * SH * SS;

  bf16x8 qf[2];
#pragma unroll
  for (int ks = 0; ks < 2; ++ks)
    qf[ks] = *(const bf16x8*)(Qb + (size_t)(q0 + l15) * SH + ks * 32 + kg * 8);

  // ---- QK^T (swapped): s[kt][n][r] = S[k = kv0+kt*64+n*16+kg*4+r][q = q0+l15]
  f32x4 s[4][4];
#pragma unroll
  for (int kt = 0; kt < 4; ++kt)
#pragma unroll
    for (int n = 0; n < 4; ++n) s[kt][n] = f32x4{0.f, 0.f, 0.f, 0.f};

  for (int kt = 0; kt < 4; ++kt) {
#pragma unroll
    for (int ks = 0; ks < 2; ++ks)
#pragma unroll
      for (int n = 0; n < 4; ++n) {
        bf16x8 kf = *(const bf16x8*)(Kbb + (size_t)(kv0 + kt * 64 + n * 16 + l15) * SH + ks * 32 + kg * 8);
        s[kt][n] = __builtin_amdgcn_mfma_f32_16x16x32_bf16(kf, qf[ks], s[kt][n], 0, 0, 0);
      }
  }

  // ---- local softmax stats; lane owns one q-row, 64 k-values
  float mloc = -1e30f;
#pragma unroll
  for (int kt = 0; kt < 4; ++kt)
#pragma unroll
    for (int n = 0; n < 4; ++n)
#pragma unroll
      for (int r = 0; r < 4; ++r) mloc = fmaxf(mloc, s[kt][n][r]);
  mloc *= 0.125f;
  mloc = fmaxf(mloc, __shfl_xor(mloc, 16));
  mloc = fmaxf(mloc, __shfl_xor(mloc, 32));

  float ssum = 0.f;
#pragma unroll
  for (int kt = 0; kt < 4; ++kt)
#pragma unroll
    for (int n = 0; n < 4; ++n)
#pragma unroll
      for (int r = 0; r < 4; ++r) {
        float e = __expf(s[kt][n][r] * 0.125f - mloc);
        s[kt][n][r] = e;
        ssum += e;
      }
  ssum += __shfl_xor(ssum, 16);
  ssum += __shfl_xor(ssum, 32);

  if (lane < 16) {
    mS[w][l15] = mloc;
    sgS[w][l15] = ssum;
  }
  __syncthreads();

  // ---- global stats -> per-lane scale for its q-row
  float M = -1e30f;
#pragma unroll
  for (int ww = 0; ww < 8; ++ww) M = fmaxf(M, mS[ww][l15]);
  float Sg = 0.f;
#pragma unroll
  for (int ww = 0; ww < 8; ++ww) Sg += sgS[ww][l15] * __expf(mS[ww][l15] - M);
  float scal = __expf(mloc - M) / Sg;

  float* wtp = wts + (size_t)b * SS * SS + (size_t)q0 * SS + kv0;
  f32x4 oacc[4];
#pragma unroll
  for (int nh = 0; nh < 4; ++nh) oacc[nh] = f32x4{0.f, 0.f, 0.f, 0.f};

  // ---- per 64-key tile: normalize -> f32 LDS slice -> {coalesced stores, PV}
  for (int kt = 0; kt < 4; ++kt) {
    // lane writes its 16 cols of row l15 (4x b128), own-wave slice only
#pragma unroll
    for (int n = 0; n < 4; ++n) {
      f32x4 pv;
#pragma unroll
      for (int r = 0; r < 4; ++r) pv[r] = s[kt][n][r] * scal;
      *(f32x4*)&pf[w][l15][n * 16 + kg * 4] = pv;
    }

    // coalesced weight stores: 16 lanes x 16B contiguous per row, 4 rows/instr
#pragma unroll
    for (int i = 0; i < 4; ++i) {
      int row = i * 4 + kg;
      f32x4 pv4 = *(const f32x4*)&pf[w][row][l15 * 4];
      *(f32x4*)(wtp + (size_t)row * SS + kt * 64 + l15 * 4) = pv4;
    }

    // PV: A-frag = row l15, k = ks*32+kg*8.. from the same slice
#pragma unroll
    for (int ks = 0; ks < 2; ++ks) {
      f32x4 pa = *(const f32x4*)&pf[w][l15][ks * 32 + kg * 8];
      f32x4 pb = *(const f32x4*)&pf[w][l15][ks * 32 + kg * 8 + 4];
      union { unsigned short us[8]; bf16x8 v; } pu;
#pragma unroll
      for (int i = 0; i < 4; ++i) { pu.us[i] = f2bf(pa[i]); pu.us[4 + i] = f2bf(pb[i]); }
#pragma unroll
      for (int nh = 0; nh < 4; ++nh) {
        bf16x8 vf = *(const bf16x8*)(Vtb + (size_t)(nh * 16 + l15) * SS + kv0 + kt * 64 + ks * 32 + kg * 8);
        oacc[nh] = __builtin_amdgcn_mfma_f32_16x16x32_bf16(pu.v, vf, oacc[nh], 0, 0, 0);
      }
    }
  }

  // ---- combine partial PV across the 8 waves (pf reused; own-slice writes)
#pragma unroll
  for (int nh = 0; nh < 4; ++nh)
#pragma unroll
    for (int r = 0; r < 4; ++r)
      pf[w][kg * 4 + r][nh * 16 + l15] = oacc[nh][r];
  __syncthreads();

  int tid = threadIdx.x;
#pragma unroll
  for (int half = 0; half < 2; ++half) {
    int e = tid + half * 512;
    int row = e >> 6, col = e & 63;
    float ssum2 = 0.f;
#pragma unroll
    for (int ww = 0; ww < 8; ++ww) ssum2 += pf[ww][row][col];
    out[((size_t)b * SS + q0 + row) * SH + col] = ssum2;
  }
}

extern "C" void kernel_launch(void* const* d_in, const int* in_sizes, int n_in,
                              void* d_out, int out_size, void* d_ws, size_t ws_size,
                              hipStream_t stream) {
  const float* x  = (const float*)d_in[0];
  const float* Wq = (const float*)d_in[1];
  const float* Wk = (const float*)d_in[2];
  const float* Wv = (const float*)d_in[3];

  unsigned short* Wt = (unsigned short*)d_ws;                 // 192*1024
  unsigned short* Q  = Wt + 192 * 1024;                       // 16384*64
  unsigned short* K  = Q + 16384 * 64;                        // 16384*64
  unsigned short* Vt = K + 16384 * 64;                        // 8*64*2048

  float* out = (float*)d_out;
  float* wts = out + (size_t)SB * SS * SH;

  prep_wt<<<768, 256, 0, stream>>>(Wq, Wk, Wv, Wt);
  proj<<<256, 512, 0, stream>>>(x, Wt, Q, K, Vt);
  attn<<<1024, 512, 0, stream>>>(Q, K, Vt, out, wts);
}